// Round 2
// baseline (581.020 us; speedup 1.0000x reference)
//
#include <hip/hip_runtime.h>
#include <hip/hip_bf16.h>
#include <cstdint>
#include <cstddef>

// Problem constants
#define B_    4
#define N_    1024
#define CIN_  256
#define HW_   256      // H == W == 256
#define D_    512
#define INK_  2304     // CIN * PH * PW
#define BN_   4096     // B * N

typedef __attribute__((ext_vector_type(8))) short bf16x8;
typedef __attribute__((ext_vector_type(4))) float f32x4;
typedef __attribute__((ext_vector_type(4))) unsigned short us4;

#define AS1(p) ((const __attribute__((address_space(1))) void*)(p))
#define AS3(p) ((__attribute__((address_space(3))) void*)(p))

__device__ __forceinline__ unsigned short f2bf(float f) {
    union { float f; unsigned u; } v; v.f = f;
    unsigned r = v.u + 0x7fffu + ((v.u >> 16) & 1u);   // round-to-nearest-even
    return (unsigned short)(r >> 16);
}

// ---------------------------------------------------------------------------
// Generic 64x64 tiled transpose: src fp32 (Mrows, Ncols) -> dst (Ncols, Mrows)
// as OutT (ushort => bf16-convert, float => copy). Coalesced both directions.
// ---------------------------------------------------------------------------
template <typename OutT>
__global__ __launch_bounds__(256) void k_t64(
    const float* __restrict__ src, OutT* __restrict__ dst,
    int Mrows, int Ncols, size_t sBatch, size_t dBatch)
{
    constexpr int PAD = (sizeof(OutT) == 2) ? 66 : 67;
    __shared__ OutT tile[64][PAD];
    const int n0 = blockIdx.x * 64;
    const int m0 = blockIdx.y * 64;
    const float* s = src + (size_t)blockIdx.z * sBatch;
    OutT* d = dst + (size_t)blockIdx.z * dBatch;
    const int t  = threadIdx.x;
    const int rr = t >> 4;          // 0..15
    const int cc = t & 15;          // 0..15

    #pragma unroll
    for (int i = 0; i < 4; ++i) {
        int row = i * 16 + rr;
        float4 v = *(const float4*)(s + (size_t)(m0 + row) * Ncols + n0 + cc * 4);
        if constexpr (sizeof(OutT) == 2) {
            tile[row][cc * 4 + 0] = f2bf(v.x);
            tile[row][cc * 4 + 1] = f2bf(v.y);
            tile[row][cc * 4 + 2] = f2bf(v.z);
            tile[row][cc * 4 + 3] = f2bf(v.w);
        } else {
            tile[row][cc * 4 + 0] = v.x;
            tile[row][cc * 4 + 1] = v.y;
            tile[row][cc * 4 + 2] = v.z;
            tile[row][cc * 4 + 3] = v.w;
        }
    }
    __syncthreads();
    #pragma unroll
    for (int i = 0; i < 4; ++i) {
        int p = i * 16 + rr;
        OutT v0 = tile[cc * 4 + 0][p];
        OutT v1 = tile[cc * 4 + 1][p];
        OutT v2 = tile[cc * 4 + 2][p];
        OutT v3 = tile[cc * 4 + 3][p];
        OutT* dp = d + (size_t)(n0 + p) * Mrows + m0 + cc * 4;
        if constexpr (sizeof(OutT) == 2) {
            *(us4*)dp = (us4){(unsigned short)v0, (unsigned short)v1,
                              (unsigned short)v2, (unsigned short)v3};
        } else {
            *(float4*)dp = make_float4(v0, v1, v2, v3);
        }
    }
}

// ---------------------------------------------------------------------------
// ROI-align gather from NHWC bf16 featsT (B, HW, CIN).
// Block = 8 boxes x 32 channel-octets (256 threads). Each load is uint4
// (16 B = 8 channels); a half-wave's 32 lanes cover 256 channels = 512 B
// contiguous. Halves the load-instruction count vs the 8 B version.
// ---------------------------------------------------------------------------
__global__ __launch_bounds__(256) void k_roi4(
    const unsigned short* __restrict__ featsT, const float* __restrict__ boxes,
    unsigned short* __restrict__ flat)
{
    __shared__ int   so[8][36][4];
    __shared__ float sw[8][36][4];
    const int t = threadIdx.x;

    // 8 boxes x 36 samples = 288 setup items over 256 threads.
    for (int s0 = t; s0 < 288; s0 += 256) {
        const int mbx = s0 / 36, s = s0 - mbx * 36;
        const int mbn = blockIdx.x * 8 + mbx;
        const float* bx = boxes + (size_t)mbn * 8;
        float xmn = fminf(fminf(bx[0], bx[2]), fminf(bx[4], bx[6]));
        float xmx = fmaxf(fmaxf(bx[0], bx[2]), fmaxf(bx[4], bx[6]));
        float ymn = fminf(fminf(bx[1], bx[3]), fminf(bx[5], bx[7]));
        float ymx = fmaxf(fmaxf(bx[1], bx[3]), fmaxf(bx[5], bx[7]));
        float sx1 = xmn * 0.25f, sy1 = ymn * 0.25f;
        float sx2 = xmx * 0.25f, sy2 = ymx * 0.25f;
        float rw = fmaxf(sx2 - sx1, 1.0f), rh = fmaxf(sy2 - sy1, 1.0f);
        float binw = rw * (1.0f / 3.0f), binh = rh * (1.0f / 3.0f);
        int row = s / 6, col = s % 6;
        float y = sy1 + (row * 0.5f + 0.25f) * binh;
        float x = sx1 + (col * 0.5f + 0.25f) * binw;
        float valid = (y > -1.0f && y < 256.0f && x > -1.0f && x < 256.0f) ? 1.0f : 0.0f;
        y = fminf(fmaxf(y, 0.0f), 255.0f);
        x = fminf(fmaxf(x, 0.0f), 255.0f);
        int y0 = (int)floorf(y), x0 = (int)floorf(x);
        int y1 = min(y0 + 1, 255), x1 = min(x0 + 1, 255);
        float ly = y - (float)y0, lx = x - (float)x0;
        float hy = 1.0f - ly, hx = 1.0f - lx;
        float m = 0.25f * valid;
        so[mbx][s][0] = y0 * HW_ + x0;  so[mbx][s][1] = y0 * HW_ + x1;
        so[mbx][s][2] = y1 * HW_ + x0;  so[mbx][s][3] = y1 * HW_ + x1;
        sw[mbx][s][0] = hy * hx * m;    sw[mbx][s][1] = hy * lx * m;
        sw[mbx][s][2] = ly * hx * m;    sw[mbx][s][3] = ly * lx * m;
    }
    __syncthreads();

    const int bxi = t >> 5;          // local box 0..7
    const int tid = t & 31;          // channel-octet
    const int bn  = blockIdx.x * 8 + bxi;
    const int b   = bn >> 10;
    // featsT viewed as uint4: pixel stride = 256ch*2B/16 = 32; image = 65536*32.
    const uint4* basep = (const uint4*)featsT + (size_t)b * (65536ull * 32ull) + tid;

    float a[8][9] = {};              // all indices static after unroll
    #pragma unroll
    for (int j = 0; j < 36; ++j) {
        const int bin = ((j / 6) >> 1) * 3 + ((j % 6) >> 1);
        #pragma unroll
        for (int p = 0; p < 4; ++p) {
            float wgt = sw[bxi][j][p];
            uint4 u = basep[(size_t)so[bxi][j][p] << 5];
            a[0][bin] += wgt * __uint_as_float(u.x << 16);
            a[1][bin] += wgt * __uint_as_float(u.x & 0xffff0000u);
            a[2][bin] += wgt * __uint_as_float(u.y << 16);
            a[3][bin] += wgt * __uint_as_float(u.y & 0xffff0000u);
            a[4][bin] += wgt * __uint_as_float(u.z << 16);
            a[5][bin] += wgt * __uint_as_float(u.z & 0xffff0000u);
            a[6][bin] += wgt * __uint_as_float(u.w << 16);
            a[7][bin] += wgt * __uint_as_float(u.w & 0xffff0000u);
        }
    }

    // flat[bn][(tid*8 + c)*9 + bin]  ==  flat[bn] + tid*72 shorts (144 B, 16-aligned)
    unsigned short tmp[72];
    #pragma unroll
    for (int c = 0; c < 8; ++c)
        #pragma unroll
        for (int k = 0; k < 9; ++k)
            tmp[c * 9 + k] = f2bf(a[c][k]);
    uint4* dst = (uint4*)(flat + (size_t)bn * INK_ + tid * 72);
    #pragma unroll
    for (int m = 0; m < 9; ++m) {
        uint4 v;
        v.x = (unsigned)tmp[8 * m + 0] | ((unsigned)tmp[8 * m + 1] << 16);
        v.y = (unsigned)tmp[8 * m + 2] | ((unsigned)tmp[8 * m + 3] << 16);
        v.z = (unsigned)tmp[8 * m + 4] | ((unsigned)tmp[8 * m + 5] << 16);
        v.w = (unsigned)tmp[8 * m + 6] | ((unsigned)tmp[8 * m + 7] << 16);
        dst[m] = v;
    }
}

// ---------------------------------------------------------------------------
// GEMM1: m97-style bf16 MFMA, C = A(MxK) * Bt(NxK)^T + bias, ReLU, bf16 out.
// Tile 128x64, BK=32, global_load_lds staging, LDS double-buffer.
// Bank-conflict fix (T2 both-sides): stage source chunk c4 ^= (r4>>2) via the
// per-lane GLOBAL address (LDS dest stays linear), read chunk q ^= (lane16>>2).
// 16 lanes then tile all 32 banks -> conflict-free ds_read_b128.
// ---------------------------------------------------------------------------
template <int K, bool RELU_BF16OUT>
__global__ __launch_bounds__(256) void k_gemmB(
    const unsigned short* __restrict__ A,
    const unsigned short* __restrict__ Bt,
    const float* __restrict__ bias,
    unsigned short* __restrict__ Cbf,
    float* __restrict__ Cf)
{
    __shared__ __align__(16) unsigned short As[2][128 * 32];  // row stride 64 B
    __shared__ __align__(16) unsigned short Bs[2][64 * 32];

    const int t = threadIdx.x;
    const int w = t >> 6;
    const int lane = t & 63;
    const int lane16 = lane & 15;
    const int q = lane >> 4;
    const int m0 = blockIdx.x * 128;
    const int n0 = blockIdx.y * 64;

    const int r4 = lane >> 2, c4 = lane & 3;
    const int c4s = c4 ^ (r4 >> 2);                  // swizzled source chunk
    const unsigned short* gA0 = A + (size_t)(m0 + w * 16 + r4) * K + c4s * 8;
    const unsigned short* gA1 = gA0 + (size_t)64 * K;
    const unsigned short* gB  = Bt + (size_t)(n0 + w * 16 + r4) * K + c4s * 8;

    const int qs = q ^ ((lane16 >> 2) & 3);          // swizzled read chunk

    f32x4 acc[2][4] = {};

    __builtin_amdgcn_global_load_lds(AS1(gA0), AS3(&As[0][(w * 16) * 32]), 16, 0, 0);
    __builtin_amdgcn_global_load_lds(AS1(gA1), AS3(&As[0][(64 + w * 16) * 32]), 16, 0, 0);
    __builtin_amdgcn_global_load_lds(AS1(gB ), AS3(&Bs[0][(w * 16) * 32]), 16, 0, 0);
    gA0 += 32; gA1 += 32; gB += 32;

    int cur = 0;
    for (int k0 = 0; k0 < K; k0 += 32) {
        __syncthreads();                    // buf[cur] ready (vmcnt drained)
        if (k0 + 32 < K) {                  // prefetch k+1 into buf[cur^1]
            __builtin_amdgcn_global_load_lds(AS1(gA0), AS3(&As[cur ^ 1][(w * 16) * 32]), 16, 0, 0);
            __builtin_amdgcn_global_load_lds(AS1(gA1), AS3(&As[cur ^ 1][(64 + w * 16) * 32]), 16, 0, 0);
            __builtin_amdgcn_global_load_lds(AS1(gB ), AS3(&Bs[cur ^ 1][(w * 16) * 32]), 16, 0, 0);
            gA0 += 32; gA1 += 32; gB += 32;
        }
        bf16x8 a0 = *(const bf16x8*)&As[cur][(w * 32 + lane16) * 32 + qs * 8];
        bf16x8 a1 = *(const bf16x8*)&As[cur][(w * 32 + 16 + lane16) * 32 + qs * 8];
        #pragma unroll
        for (int nt = 0; nt < 4; ++nt) {
            bf16x8 bv = *(const bf16x8*)&Bs[cur][(nt * 16 + lane16) * 32 + qs * 8];
            acc[0][nt] = __builtin_amdgcn_mfma_f32_16x16x32_bf16(a0, bv, acc[0][nt], 0, 0, 0);
            acc[1][nt] = __builtin_amdgcn_mfma_f32_16x16x32_bf16(a1, bv, acc[1][nt], 0, 0, 0);
        }
        cur ^= 1;
    }

    #pragma unroll
    for (int nt = 0; nt < 4; ++nt) {
        int col = n0 + nt * 16 + lane16;
        float bs = bias[col];
        #pragma unroll
        for (int mg = 0; mg < 2; ++mg) {
            #pragma unroll
            for (int r = 0; r < 4; ++r) {
                int row = m0 + w * 32 + mg * 16 + q * 4 + r;
                float v = acc[mg][nt][r] + bs;
                if constexpr (RELU_BF16OUT) {
                    v = fmaxf(v, 0.0f);
                    Cbf[(size_t)row * D_ + col] = f2bf(v);
                } else {
                    Cf[(size_t)row * D_ + col] = v;
                }
            }
        }
    }
}

// ---------------------------------------------------------------------------
// Fused GEMM2 + bias + pos-matvec + LN1 + add + LN2 + transposed store + mask.
// Grid = 256 blocks x 256 threads. Block = 16 rows (boxes) x all 512 cols.
// W2t staged via double-buffered global_load_lds (LDS exactly 64 KB);
// same T2 both-sides chunk swizzle as k_gemmB on the Bs tile.
// ---------------------------------------------------------------------------
__global__ __launch_bounds__(256) void k_fuse2(
    const unsigned short* __restrict__ act,   // (4096,512) bf16
    const unsigned short* __restrict__ W2t,   // (512,512) bf16, row=n, K-contig
    const float* __restrict__ b2,
    const float* __restrict__ boxes,
    const float* __restrict__ img_sizes,
    const float* __restrict__ Wb,  const float* __restrict__ bbv,
    const float* __restrict__ g1,  const float* __restrict__ be1,
    const float* __restrict__ g2,  const float* __restrict__ be2,
    float* __restrict__ out)
{
    __shared__ __align__(16) unsigned short Bs[2][512 * 32];   // 2 x 32 KB
    float* S2 = (float*)&Bs[0][0];   // 16 x 512 fp32 = 32 KB, aliases Bs[0]

    const int t = threadIdx.x;
    const int w = t >> 6, l = t & 63;
    const int lane16 = l & 15, q = l >> 4;
    const int m0 = blockIdx.x * 16;
    const int b  = m0 >> 10;

    // B staging: thread t stages rows r = (t>>2) + 64*i, swizzled chunk
    // c_g = (t&3) ^ ((t>>4)&3) (row>>2 mod 4 is (t>>4)&3 for ALL i since
    // i*64>>2 = i*16 ≡ 0 mod 4). LDS dest stays linear (= uniform + t*16 B).
    const unsigned short* gB = W2t + (size_t)(t >> 2) * D_
                             + (size_t)(((t & 3) ^ ((t >> 4) & 3)) * 8);
    #pragma unroll
    for (int i = 0; i < 8; ++i)
        __builtin_amdgcn_global_load_lds(AS1(gB + (size_t)i * 64 * D_),
            AS3(&Bs[0][(t >> 2) * 32 + (t & 3) * 8 + i * 2048]), 16, 0, 0);

    const int qs = q ^ ((lane16 >> 2) & 3);          // swizzled read chunk

    f32x4 acc[8] = {};
    const unsigned short* gA = act + (size_t)(m0 + lane16) * D_ + q * 8;

    int cur = 0;
    for (int k0 = 0; k0 < D_; k0 += 32) {
        __syncthreads();                       // Bs[cur] staged (vmcnt drained)
        bf16x8 av = *(const bf16x8*)(gA + k0); // A direct from global (L2-hot)
        if (k0 + 32 < D_) {
            #pragma unroll
            for (int i = 0; i < 8; ++i)
                __builtin_amdgcn_global_load_lds(AS1(gB + k0 + 32 + (size_t)i * 64 * D_),
                    AS3(&Bs[cur ^ 1][(t >> 2) * 32 + (t & 3) * 8 + i * 2048]), 16, 0, 0);
        }
        #pragma unroll
        for (int nt = 0; nt < 8; ++nt) {
            bf16x8 bv = *(const bf16x8*)&Bs[cur][(w * 128 + nt * 16 + lane16) * 32 + qs * 8];
            acc[nt] = __builtin_amdgcn_mfma_f32_16x16x32_bf16(av, bv, acc[nt], 0, 0, 0);
        }
        cur ^= 1;
    }
    __syncthreads();   // all ds_reads done -> safe to overwrite Bs[0] via S2

    // acc -> S2 (+bias). C/D layout: row = q*4+r, col = lane16 (per n-tile).
    #pragma unroll
    for (int nt = 0; nt < 8; ++nt) {
        int col = w * 128 + nt * 16 + lane16;
        float bs = b2[col];
        #pragma unroll
        for (int r = 0; r < 4; ++r)
            S2[(q * 4 + r) * D_ + col] = acc[nt][r] + bs;
    }
    __syncthreads();

    // Per-wave LN pipeline: wave w owns rows w*4 .. w*4+4 (disjoint).
    const float si0 = img_sizes[b * 2], si1 = img_sizes[b * 2 + 1];
    #pragma unroll 1
    for (int j = 0; j < 4; ++j) {
        const int rho = w * 4 + j;
        const float* bx = boxes + (size_t)(m0 + rho) * 8;
        float xmn = fminf(fminf(bx[0], bx[2]), fminf(bx[4], bx[6]));
        float xmx = fmaxf(fmaxf(bx[0], bx[2]), fmaxf(bx[4], bx[6]));
        float ymn = fminf(fminf(bx[1], bx[3]), fminf(bx[5], bx[7]));
        float ymx = fmaxf(fmaxf(bx[1], bx[3]), fmaxf(bx[5], bx[7]));
        float q0 = xmn / si0, q1 = ymn / si1, q2 = xmx / si0, q3 = ymx / si1;

        float tp[8], su = 0.f, sq = 0.f;
        #pragma unroll
        for (int i = 0; i < 8; ++i) {
            int d = i * 64 + l;
            float v = q0 * Wb[d] + q1 * Wb[512 + d] + q2 * Wb[1024 + d]
                    + q3 * Wb[1536 + d] + bbv[d];
            tp[i] = v; su += v; sq += v * v;
        }
        #pragma unroll
        for (int off = 32; off > 0; off >>= 1) {
            su += __shfl_xor(su, off); sq += __shfl_xor(sq, off);
        }
        float mu = su * (1.0f / 512.0f);
        float rs = rsqrtf(sq * (1.0f / 512.0f) - mu * mu + 1e-5f);

        float sv[8]; su = 0.f; sq = 0.f;
        #pragma unroll
        for (int i = 0; i < 8; ++i) {
            int d = i * 64 + l;
            float p = (tp[i] - mu) * rs * g1[d] + be1[d];
            float s = S2[rho * D_ + d] + p;
            sv[i] = s; su += s; sq += s * s;
        }
        #pragma unroll
        for (int off = 32; off > 0; off >>= 1) {
            su += __shfl_xor(su, off); sq += __shfl_xor(sq, off);
        }
        float mu2 = su * (1.0f / 512.0f);
        float rs2 = rsqrtf(sq * (1.0f / 512.0f) - mu2 * mu2 + 1e-5f);

        #pragma unroll
        for (int i = 0; i < 8; ++i) {
            int d = i * 64 + l;
            S2[rho * D_ + d] = (sv[i] - mu2) * rs2 * g2[d] + be2[d];
        }
    }
    __syncthreads();

    // Transposed store: out[b][d][nb..nb+16). 4 lanes cover 64 B per d.
    const int nb = m0 & 1023;
    float* ob = out + (size_t)b * (D_ * N_) + nb;
    const int dd = t >> 2, part = t & 3;
    #pragma unroll
    for (int i = 0; i < 8; ++i) {
        int d = i * 64 + dd;
        float4 v;
        v.x = S2[(part * 4 + 0) * D_ + d];
        v.y = S2[(part * 4 + 1) * D_ + d];
        v.z = S2[(part * 4 + 2) * D_ + d];
        v.w = S2[(part * 4 + 3) * D_ + d];
        *(float4*)(ob + (size_t)d * N_ + part * 4) = v;
    }
    if (t < 16) out[(size_t)B_ * D_ * N_ + m0 + t] = 1.0f;   // masks
}

// ---------------------------------------------------------------------------
// FALLBACK path kernels (ws too small): round-1 NCHW gather + weight convert
// + 64x64 VGPR-staged GEMM + standalone tail/mask.
// ---------------------------------------------------------------------------
__global__ __launch_bounds__(256) void k_convert(
    const float* __restrict__ W1, const float* __restrict__ W2,
    unsigned short* __restrict__ W1t, unsigned short* __restrict__ W2t)
{
    int i = blockIdx.x * 256 + threadIdx.x;
    const int n1 = INK_ * D_;
    if (i < n1) {
        int n = i / INK_, k = i % INK_;
        W1t[i] = f2bf(W1[(size_t)k * D_ + n]);
    } else {
        int j = i - n1;
        if (j < D_ * D_) {
            int n = j / D_, k = j % D_;
            W2t[j] = f2bf(W2[(size_t)k * D_ + n]);
        }
    }
}

__global__ __launch_bounds__(256) void k_roi(
    const float* __restrict__ feats, const float* __restrict__ boxes,
    unsigned short* __restrict__ flat)
{
    __shared__ int   so[36][4];
    __shared__ float sw[36][4];
    const int bn = blockIdx.x;
    const int b  = bn >> 10;
    const int t  = threadIdx.x;

    if (t < 36) {
        const float* bx = boxes + (size_t)bn * 8;
        float xmn = fminf(fminf(bx[0], bx[2]), fminf(bx[4], bx[6]));
        float xmx = fmaxf(fmaxf(bx[0], bx[2]), fmaxf(bx[4], bx[6]));
        float ymn = fminf(fminf(bx[1], bx[3]), fminf(bx[5], bx[7]));
        float ymx = fmaxf(fmaxf(bx[1], bx[3]), fmaxf(bx[5], bx[7]));
        float sx1 = xmn * 0.25f, sy1 = ymn * 0.25f;
        float sx2 = xmx * 0.25f, sy2 = ymx * 0.25f;
        float rw = fmaxf(sx2 - sx1, 1.0f), rh = fmaxf(sy2 - sy1, 1.0f);
        float binw = rw * (1.0f / 3.0f), binh = rh * (1.0f / 3.0f);
        int row = t / 6, col = t % 6;
        float y = sy1 + (row * 0.5f + 0.25f) * binh;
        float x = sx1 + (col * 0.5f + 0.25f) * binw;
        float valid = (y > -1.0f && y < 256.0f && x > -1.0f && x < 256.0f) ? 1.0f : 0.0f;
        y = fminf(fmaxf(y, 0.0f), 255.0f);
        x = fminf(fmaxf(x, 0.0f), 255.0f);
        int y0 = (int)floorf(y), x0 = (int)floorf(x);
        int y1 = min(y0 + 1, 255), x1 = min(x0 + 1, 255);
        float ly = y - (float)y0, lx = x - (float)x0;
        float hy = 1.0f - ly, hx = 1.0f - lx;
        float m = 0.25f * valid;
        so[t][0] = y0 * HW_ + x0;  so[t][1] = y0 * HW_ + x1;
        so[t][2] = y1 * HW_ + x0;  so[t][3] = y1 * HW_ + x1;
        sw[t][0] = hy * hx * m;    sw[t][1] = hy * lx * m;
        sw[t][2] = ly * hx * m;    sw[t][3] = ly * lx * m;
    }
    __syncthreads();

    const float* base = feats + ((size_t)(b * CIN_ + t) << 16);
    float acc[9] = {0.f,0.f,0.f,0.f,0.f,0.f,0.f,0.f,0.f};
    #pragma unroll
    for (int j = 0; j < 36; ++j) {
        const int bin = ((j / 6) >> 1) * 3 + ((j % 6) >> 1);
        float v = sw[j][0] * base[so[j][0]] + sw[j][1] * base[so[j][1]]
                + sw[j][2] * base[so[j][2]] + sw[j][3] * base[so[j][3]];
        acc[bin] += v;
    }
    unsigned short* dst = flat + (size_t)bn * INK_ + t * 9;
    #pragma unroll
    for (int k = 0; k < 9; ++k) dst[k] = f2bf(acc[k]);
}

template <int K, bool RELU_BF16OUT>
__global__ __launch_bounds__(256) void k_gemm(
    const unsigned short* __restrict__ A,
    const unsigned short* __restrict__ Bt,
    const float* __restrict__ bias,
    unsigned short* __restrict__ Cbf,
    float* __restrict__ Cf)
{
    __shared__ __align__(16) unsigned short Asl[64 * 40];
    __shared__ __align__(16) unsigned short Bsl[64 * 40];

    const int t  = threadIdx.x;
    const int m0 = blockIdx.x * 64;
    const int n0 = blockIdx.y * 64;
    const int w  = t >> 6;
    const int l  = t & 63;
    const int lane16 = l & 15;
    const int q  = l >> 4;

    f32x4 acc[4] = {};

    const int srow = t >> 2;
    const int sch  = t & 3;
    const unsigned short* ga = A  + (size_t)(m0 + srow) * K + sch * 8;
    const unsigned short* gb = Bt + (size_t)(n0 + srow) * K + sch * 8;
    unsigned short* la = &Asl[srow * 40 + sch * 8];
    unsigned short* lb = &Bsl[srow * 40 + sch * 8];

    for (int k0 = 0; k0 < K; k0 += 32) {
        __syncthreads();
        *(bf16x8*)la = *(const bf16x8*)(ga + k0);
        *(bf16x8*)lb = *(const bf16x8*)(gb + k0);
        __syncthreads();
        bf16x8 af = *(const bf16x8*)&Asl[(w * 16 + lane16) * 40 + q * 8];
        #pragma unroll
        for (int nt = 0; nt < 4; ++nt) {
            bf16x8 bfv = *(const bf16x8*)&Bsl[(nt * 16 + lane16) * 40 + q * 8];
            acc[nt] = __builtin_amdgcn_mfma_f32_16x16x32_bf16(af, bfv, acc[nt], 0, 0, 0);
        }
    }

    #pragma unroll
    for (int nt = 0; nt < 4; ++nt) {
        int col = n0 + nt * 16 + lane16;
        float bs = bias[col];
        #pragma unroll
        for (int r = 0; r < 4; ++r) {
            int rowg = m0 + w * 16 + q * 4 + r;
            float v = acc[nt][r] + bs;
            if constexpr (RELU_BF16OUT) {
                v = fmaxf(v, 0.0f);
                Cbf[(size_t)rowg * D_ + col] = f2bf(v);
            } else {
                Cf[(size_t)rowg * D_ + col] = v;
            }
        }
    }
}

__device__ __forceinline__ void breduce2(float& a, float& b, float* red, int t) {
    #pragma unroll
    for (int off = 32; off > 0; off >>= 1) {
        a += __shfl_down(a, off);
        b += __shfl_down(b, off);
    }
    int w = t >> 6;
    if ((t & 63) == 0) { red[w] = a; red[4 + w] = b; }
    __syncthreads();
    a = red[0] + red[1] + red[2] + red[3];
    b = red[4] + red[5] + red[6] + red[7];
    __syncthreads();
}

__global__ __launch_bounds__(256) void k_tail(
    const float* __restrict__ lines, const float* __restrict__ boxes,
    const float* __restrict__ img_sizes,
    const float* __restrict__ Wb,  const float* __restrict__ bbv,
    const float* __restrict__ g1,  const float* __restrict__ be1,
    const float* __restrict__ g2,  const float* __restrict__ be2,
    float* __restrict__ out)
{
    __shared__ float red[8];
    const int row = blockIdx.x;
    const int b = row >> 10, n = row & 1023;
    const int t = threadIdx.x;

    const float* bx = boxes + (size_t)row * 8;
    float xmn = fminf(fminf(bx[0], bx[2]), fminf(bx[4], bx[6]));
    float xmx = fmaxf(fmaxf(bx[0], bx[2]), fmaxf(bx[4], bx[6]));
    float ymn = fminf(fminf(bx[1], bx[3]), fminf(bx[5], bx[7]));
    float ymx = fmaxf(fmaxf(bx[1], bx[3]), fmaxf(bx[5], bx[7]));
    float s0 = img_sizes[b * 2], s1 = img_sizes[b * 2 + 1];
    float q0 = xmn / s0, q1 = ymn / s1, q2 = xmx / s0, q3 = ymx / s1;

    float tv[2], sv[2];
    float sum = 0.f, sumsq = 0.f;
    #pragma unroll
    for (int i = 0; i < 2; ++i) {
        int d = t + i * 256;
        float v = q0 * Wb[d] + q1 * Wb[512 + d] + q2 * Wb[1024 + d] + q3 * Wb[1536 + d] + bbv[d];
        tv[i] = v; sum += v; sumsq += v * v;
    }
    breduce2(sum, sumsq, red, t);
    float mu = sum * (1.0f / 512.0f);
    float var = sumsq * (1.0f / 512.0f) - mu * mu;
    float rs = rsqrtf(var + 1e-5f);

    sum = 0.f; sumsq = 0.f;
    #pragma unroll
    for (int i = 0; i < 2; ++i) {
        int d = t + i * 256;
        float p = (tv[i] - mu) * rs * g1[d] + be1[d];
        float s = lines[(size_t)row * D_ + d] + p;
        sv[i] = s; sum += s; sumsq += s * s;
    }
    breduce2(sum, sumsq, red, t);
    float mu2 = sum * (1.0f / 512.0f);
    float var2 = sumsq * (1.0f / 512.0f) - mu2 * mu2;
    float rs2 = rsqrtf(var2 + 1e-5f);

    #pragma unroll
    for (int i = 0; i < 2; ++i) {
        int d = t + i * 256;
        float o = (sv[i] - mu2) * rs2 * g2[d] + be2[d];
        out[(size_t)b * (D_ * N_) + (size_t)d * N_ + n] = o;
    }
}

__global__ __launch_bounds__(256) void k_mask(float* __restrict__ out) {
    int i = blockIdx.x * 256 + threadIdx.x;
    if (i < B_ * 32 * 32) out[(size_t)B_ * D_ * N_ + i] = 1.0f;
}

// ---------------------------------------------------------------------------
extern "C" void kernel_launch(void* const* d_in, const int* in_sizes, int n_in,
                              void* d_out, int out_size, void* d_ws, size_t ws_size,
                              hipStream_t stream)
{
    const float* feats = (const float*)d_in[0];
    const float* boxes = (const float*)d_in[1];
    const float* img   = (const float*)d_in[2];
    const float* W1    = (const float*)d_in[3];
    const float* b1    = (const float*)d_in[4];
    const float* W2    = (const float*)d_in[5];
    const float* b2    = (const float*)d_in[6];
    const float* Wb    = (const float*)d_in[7];
    const float* bbv   = (const float*)d_in[8];
    const float* g1    = (const float*)d_in[9];
    const float* be1   = (const float*)d_in[10];
    const float* g2    = (const float*)d_in[11];
    const float* be2   = (const float*)d_in[12];
    float* out = (float*)d_out;
    char* ws = (char*)d_ws;

    // Fast-path ws layout (bytes):
    const size_t OFF_FEATST = 0;                         // bf16 4x65536x256 = 134,217,728
    const size_t OFF_W1T    = 134217728;                 // bf16 512x2304   =   2,359,296
    const size_t OFF_W2T    = 136577024;                 // bf16 512x512    =     524,288
    const size_t OFF_FLAT   = 137101312;                 // bf16 4096x2304  =  18,874,368
    const size_t OFF_ACT    = 155975680;                 // bf16 4096x512   =   4,194,304
    const size_t NEED       = 160169984;

    if (ws_size >= NEED) {
        unsigned short* featsT = (unsigned short*)(ws + OFF_FEATST);
        unsigned short* W1t    = (unsigned short*)(ws + OFF_W1T);
        unsigned short* W2t    = (unsigned short*)(ws + OFF_W2T);
        unsigned short* flat   = (unsigned short*)(ws + OFF_FLAT);
        unsigned short* act    = (unsigned short*)(ws + OFF_ACT);

        // feats (B,CIN,HW) f32 -> featsT (B,HW,CIN) bf16
        k_t64<unsigned short><<<dim3(HW_*HW_/64, CIN_/64, B_), 256, 0, stream>>>(
            feats, featsT, CIN_, HW_*HW_, (size_t)CIN_*HW_*HW_, (size_t)CIN_*HW_*HW_);
        // W1 (2304,512) -> W1t (512,2304) bf16 ; W2 (512,512) -> W2t
        k_t64<unsigned short><<<dim3(D_/64, INK_/64, 1), 256, 0, stream>>>(
            W1, W1t, INK_, D_, 0, 0);
        k_t64<unsigned short><<<dim3(D_/64, D_/64, 1), 256, 0, stream>>>(
            W2, W2t, D_, D_, 0, 0);

        k_roi4<<<BN_/8, 256, 0, stream>>>(featsT, boxes, flat);

        dim3 gg(32, 8);   // M/128 x N/64 = 256 blocks
        k_gemmB<INK_, true><<<gg, 256, 0, stream>>>(flat, W1t, b1, act, nullptr);

        // Fused GEMM2 + LN pipeline + transposed store + mask
        k_fuse2<<<BN_/16, 256, 0, stream>>>(act, W2t, b2, boxes, img,
                                            Wb, bbv, g1, be1, g2, be2, out);
    } else {
        // Fallback: round-1 path (34,340,864 bytes of ws)
        unsigned short* W1t  = (unsigned short*)(ws);
        unsigned short* W2t  = (unsigned short*)(ws + 2359296);
        unsigned short* flat = (unsigned short*)(ws + 2883584);
        unsigned short* act  = (unsigned short*)(ws + 21757952);
        float*          lines= (float*)(ws + 25952256);

        const int convTotal = INK_ * D_ + D_ * D_;
        k_convert<<<(convTotal + 255) / 256, 256, 0, stream>>>(W1, W2, W1t, W2t);
        k_roi<<<BN_, 256, 0, stream>>>(feats, boxes, flat);
        dim3 gg(64, 8);
        k_gemm<INK_, true ><<<gg, 256, 0, stream>>>(flat, W1t, b1, act, nullptr);
        k_gemm<D_,   false><<<gg, 256, 0, stream>>>(act,  W2t, b2, nullptr, lines);
        k_tail<<<BN_, 256, 0, stream>>>(lines, boxes, img, Wb, bbv, g1, be1, g2, be2, out);
        k_mask<<<16, 256, 0, stream>>>(out);
    }
}

// Round 3
// 505.079 us; speedup vs baseline: 1.1504x; 1.1504x over previous
//
#include <hip/hip_runtime.h>
#include <hip/hip_bf16.h>
#include <cstdint>
#include <cstddef>

// Problem constants
#define B_    4
#define N_    1024
#define CIN_  256
#define HW_   256      // H == W == 256
#define D_    512
#define INK_  2304     // CIN * PH * PW
#define BN_   4096     // B * N

typedef __attribute__((ext_vector_type(8))) short bf16x8;
typedef __attribute__((ext_vector_type(4))) float f32x4;
typedef __attribute__((ext_vector_type(4))) unsigned short us4;

#define AS1(p) ((const __attribute__((address_space(1))) void*)(p))
#define AS3(p) ((__attribute__((address_space(3))) void*)(p))

__device__ __forceinline__ unsigned short f2bf(float f) {
    union { float f; unsigned u; } v; v.f = f;
    unsigned r = v.u + 0x7fffu + ((v.u >> 16) & 1u);   // round-to-nearest-even
    return (unsigned short)(r >> 16);
}

// ---------------------------------------------------------------------------
// Generic 64x64 tiled transpose: src fp32 (Mrows, Ncols) -> dst (Ncols, Mrows)
// as OutT (ushort => bf16-convert, float => copy). Coalesced both directions.
// ---------------------------------------------------------------------------
template <typename OutT>
__global__ __launch_bounds__(256) void k_t64(
    const float* __restrict__ src, OutT* __restrict__ dst,
    int Mrows, int Ncols, size_t sBatch, size_t dBatch)
{
    constexpr int PAD = (sizeof(OutT) == 2) ? 66 : 67;
    __shared__ OutT tile[64][PAD];
    const int n0 = blockIdx.x * 64;
    const int m0 = blockIdx.y * 64;
    const float* s = src + (size_t)blockIdx.z * sBatch;
    OutT* d = dst + (size_t)blockIdx.z * dBatch;
    const int t  = threadIdx.x;
    const int rr = t >> 4;          // 0..15
    const int cc = t & 15;          // 0..15

    #pragma unroll
    for (int i = 0; i < 4; ++i) {
        int row = i * 16 + rr;
        float4 v = *(const float4*)(s + (size_t)(m0 + row) * Ncols + n0 + cc * 4);
        if constexpr (sizeof(OutT) == 2) {
            tile[row][cc * 4 + 0] = f2bf(v.x);
            tile[row][cc * 4 + 1] = f2bf(v.y);
            tile[row][cc * 4 + 2] = f2bf(v.z);
            tile[row][cc * 4 + 3] = f2bf(v.w);
        } else {
            tile[row][cc * 4 + 0] = v.x;
            tile[row][cc * 4 + 1] = v.y;
            tile[row][cc * 4 + 2] = v.z;
            tile[row][cc * 4 + 3] = v.w;
        }
    }
    __syncthreads();
    #pragma unroll
    for (int i = 0; i < 4; ++i) {
        int p = i * 16 + rr;
        OutT v0 = tile[cc * 4 + 0][p];
        OutT v1 = tile[cc * 4 + 1][p];
        OutT v2 = tile[cc * 4 + 2][p];
        OutT v3 = tile[cc * 4 + 3][p];
        OutT* dp = d + (size_t)(n0 + p) * Mrows + m0 + cc * 4;
        if constexpr (sizeof(OutT) == 2) {
            *(us4*)dp = (us4){(unsigned short)v0, (unsigned short)v1,
                              (unsigned short)v2, (unsigned short)v3};
        } else {
            *(float4*)dp = make_float4(v0, v1, v2, v3);
        }
    }
}

// ---------------------------------------------------------------------------
// ROI-align gather from NHWC bf16 featsT (B, HW, CIN).
// Block = 4 boxes x 64 channel-quads (256 threads). Each load is uint2 (8 B,
// 4 channels); a wave's 64 lanes cover 256 channels = 512 B contiguous.
// (Reverted from the uint4/8-box variant: doubled per-lane state killed
// occupancy on this latency-bound gather; grid halving removed TLP.)
// ---------------------------------------------------------------------------
__global__ __launch_bounds__(256) void k_roi3(
    const unsigned short* __restrict__ featsT, const float* __restrict__ boxes,
    unsigned short* __restrict__ flat)
{
    __shared__ int   so[4][36][4];
    __shared__ float sw[4][36][4];
    const int t = threadIdx.x;

    if (t < 144) {
        const int mbx = t / 36, s = t - mbx * 36;
        const int mbn = blockIdx.x * 4 + mbx;
        const float* bx = boxes + (size_t)mbn * 8;
        float xmn = fminf(fminf(bx[0], bx[2]), fminf(bx[4], bx[6]));
        float xmx = fmaxf(fmaxf(bx[0], bx[2]), fmaxf(bx[4], bx[6]));
        float ymn = fminf(fminf(bx[1], bx[3]), fminf(bx[5], bx[7]));
        float ymx = fmaxf(fmaxf(bx[1], bx[3]), fmaxf(bx[5], bx[7]));
        float sx1 = xmn * 0.25f, sy1 = ymn * 0.25f;
        float sx2 = xmx * 0.25f, sy2 = ymx * 0.25f;
        float rw = fmaxf(sx2 - sx1, 1.0f), rh = fmaxf(sy2 - sy1, 1.0f);
        float binw = rw * (1.0f / 3.0f), binh = rh * (1.0f / 3.0f);
        int row = s / 6, col = s % 6;
        float y = sy1 + (row * 0.5f + 0.25f) * binh;
        float x = sx1 + (col * 0.5f + 0.25f) * binw;
        float valid = (y > -1.0f && y < 256.0f && x > -1.0f && x < 256.0f) ? 1.0f : 0.0f;
        y = fminf(fmaxf(y, 0.0f), 255.0f);
        x = fminf(fmaxf(x, 0.0f), 255.0f);
        int y0 = (int)floorf(y), x0 = (int)floorf(x);
        int y1 = min(y0 + 1, 255), x1 = min(x0 + 1, 255);
        float ly = y - (float)y0, lx = x - (float)x0;
        float hy = 1.0f - ly, hx = 1.0f - lx;
        float m = 0.25f * valid;
        so[mbx][s][0] = y0 * HW_ + x0;  so[mbx][s][1] = y0 * HW_ + x1;
        so[mbx][s][2] = y1 * HW_ + x0;  so[mbx][s][3] = y1 * HW_ + x1;
        sw[mbx][s][0] = hy * hx * m;    sw[mbx][s][1] = hy * lx * m;
        sw[mbx][s][2] = ly * hx * m;    sw[mbx][s][3] = ly * lx * m;
    }
    __syncthreads();

    const int bxi = t >> 6;          // local box 0..3
    const int tid = t & 63;          // channel-quad
    const int bn  = blockIdx.x * 4 + bxi;
    const int b   = bn >> 10;
    const uint2* basep = (const uint2*)featsT + (size_t)b * (65536ull * 64ull) + tid;

    float a0[9] = {0,0,0,0,0,0,0,0,0};
    float a1[9] = {0,0,0,0,0,0,0,0,0};
    float a2[9] = {0,0,0,0,0,0,0,0,0};
    float a3[9] = {0,0,0,0,0,0,0,0,0};
    #pragma unroll
    for (int j = 0; j < 36; ++j) {
        const int bin = ((j / 6) >> 1) * 3 + ((j % 6) >> 1);
        #pragma unroll
        for (int p = 0; p < 4; ++p) {
            float wgt = sw[bxi][j][p];
            uint2 u = basep[(size_t)so[bxi][j][p] << 6];
            a0[bin] += wgt * __uint_as_float(u.x << 16);
            a1[bin] += wgt * __uint_as_float(u.x & 0xffff0000u);
            a2[bin] += wgt * __uint_as_float(u.y << 16);
            a3[bin] += wgt * __uint_as_float(u.y & 0xffff0000u);
        }
    }

    unsigned short tmp[36];
    #pragma unroll
    for (int k = 0; k < 9; ++k) {
        tmp[k] = f2bf(a0[k]); tmp[9 + k] = f2bf(a1[k]);
        tmp[18 + k] = f2bf(a2[k]); tmp[27 + k] = f2bf(a3[k]);
    }
    unsigned* dst = (unsigned*)(flat + (size_t)bn * INK_ + tid * 36);
    #pragma unroll
    for (int k = 0; k < 18; ++k)
        dst[k] = (unsigned)tmp[2 * k] | ((unsigned)tmp[2 * k + 1] << 16);
}

// ---------------------------------------------------------------------------
// GEMM1: m97-style bf16 MFMA, C = A(MxK) * Bt(NxK)^T + bias, ReLU, bf16 out.
// Tile 128x64, BK=32, global_load_lds staging, LDS double-buffer.
// Bank-conflict fix (T2 both-sides): stage source chunk c4 ^= (r4>>2) via the
// per-lane GLOBAL address (LDS dest stays linear), read chunk q ^= (lane16>>2).
// ds_read_b128 bank-starts go from {0,16}x8-way to 8 starts x 2-way (free).
// ---------------------------------------------------------------------------
template <int K, bool RELU_BF16OUT>
__global__ __launch_bounds__(256) void k_gemmB(
    const unsigned short* __restrict__ A,
    const unsigned short* __restrict__ Bt,
    const float* __restrict__ bias,
    unsigned short* __restrict__ Cbf,
    float* __restrict__ Cf)
{
    __shared__ __align__(16) unsigned short As[2][128 * 32];  // row stride 64 B
    __shared__ __align__(16) unsigned short Bs[2][64 * 32];

    const int t = threadIdx.x;
    const int w = t >> 6;
    const int lane = t & 63;
    const int lane16 = lane & 15;
    const int q = lane >> 4;
    const int m0 = blockIdx.x * 128;
    const int n0 = blockIdx.y * 64;

    const int r4 = lane >> 2, c4 = lane & 3;
    const int c4s = c4 ^ (r4 >> 2);                  // swizzled source chunk
    const unsigned short* gA0 = A + (size_t)(m0 + w * 16 + r4) * K + c4s * 8;
    const unsigned short* gA1 = gA0 + (size_t)64 * K;
    const unsigned short* gB  = Bt + (size_t)(n0 + w * 16 + r4) * K + c4s * 8;

    const int qs = q ^ ((lane16 >> 2) & 3);          // swizzled read chunk

    f32x4 acc[2][4] = {};

    __builtin_amdgcn_global_load_lds(AS1(gA0), AS3(&As[0][(w * 16) * 32]), 16, 0, 0);
    __builtin_amdgcn_global_load_lds(AS1(gA1), AS3(&As[0][(64 + w * 16) * 32]), 16, 0, 0);
    __builtin_amdgcn_global_load_lds(AS1(gB ), AS3(&Bs[0][(w * 16) * 32]), 16, 0, 0);
    gA0 += 32; gA1 += 32; gB += 32;

    int cur = 0;
    for (int k0 = 0; k0 < K; k0 += 32) {
        __syncthreads();                    // buf[cur] ready (vmcnt drained)
        if (k0 + 32 < K) {                  // prefetch k+1 into buf[cur^1]
            __builtin_amdgcn_global_load_lds(AS1(gA0), AS3(&As[cur ^ 1][(w * 16) * 32]), 16, 0, 0);
            __builtin_amdgcn_global_load_lds(AS1(gA1), AS3(&As[cur ^ 1][(64 + w * 16) * 32]), 16, 0, 0);
            __builtin_amdgcn_global_load_lds(AS1(gB ), AS3(&Bs[cur ^ 1][(w * 16) * 32]), 16, 0, 0);
            gA0 += 32; gA1 += 32; gB += 32;
        }
        bf16x8 a0 = *(const bf16x8*)&As[cur][(w * 32 + lane16) * 32 + qs * 8];
        bf16x8 a1 = *(const bf16x8*)&As[cur][(w * 32 + 16 + lane16) * 32 + qs * 8];
        #pragma unroll
        for (int nt = 0; nt < 4; ++nt) {
            bf16x8 bv = *(const bf16x8*)&Bs[cur][(nt * 16 + lane16) * 32 + qs * 8];
            acc[0][nt] = __builtin_amdgcn_mfma_f32_16x16x32_bf16(a0, bv, acc[0][nt], 0, 0, 0);
            acc[1][nt] = __builtin_amdgcn_mfma_f32_16x16x32_bf16(a1, bv, acc[1][nt], 0, 0, 0);
        }
        cur ^= 1;
    }

    #pragma unroll
    for (int nt = 0; nt < 4; ++nt) {
        int col = n0 + nt * 16 + lane16;
        float bs = bias[col];
        #pragma unroll
        for (int mg = 0; mg < 2; ++mg) {
            #pragma unroll
            for (int r = 0; r < 4; ++r) {
                int row = m0 + w * 32 + mg * 16 + q * 4 + r;
                float v = acc[mg][nt][r] + bs;
                if constexpr (RELU_BF16OUT) {
                    v = fmaxf(v, 0.0f);
                    Cbf[(size_t)row * D_ + col] = f2bf(v);
                } else {
                    Cf[(size_t)row * D_ + col] = v;
                }
            }
        }
    }
}

// ---------------------------------------------------------------------------
// Fused GEMM2 + bias + pos-matvec + LN1 + add + LN2 + transposed store + mask.
// Grid = 256 blocks x 256 threads. Block = 16 rows (boxes) x all 512 cols.
// W2t staged via double-buffered global_load_lds (LDS exactly 64 KB);
// same T2 both-sides chunk swizzle as k_gemmB on the Bs tile.
// ---------------------------------------------------------------------------
__global__ __launch_bounds__(256) void k_fuse2(
    const unsigned short* __restrict__ act,   // (4096,512) bf16
    const unsigned short* __restrict__ W2t,   // (512,512) bf16, row=n, K-contig
    const float* __restrict__ b2,
    const float* __restrict__ boxes,
    const float* __restrict__ img_sizes,
    const float* __restrict__ Wb,  const float* __restrict__ bbv,
    const float* __restrict__ g1,  const float* __restrict__ be1,
    const float* __restrict__ g2,  const float* __restrict__ be2,
    float* __restrict__ out)
{
    __shared__ __align__(16) unsigned short Bs[2][512 * 32];   // 2 x 32 KB
    float* S2 = (float*)&Bs[0][0];   // 16 x 512 fp32 = 32 KB, aliases Bs[0]

    const int t = threadIdx.x;
    const int w = t >> 6, l = t & 63;
    const int lane16 = l & 15, q = l >> 4;
    const int m0 = blockIdx.x * 16;
    const int b  = m0 >> 10;

    // B staging: thread t stages rows r = (t>>2) + 64*i, swizzled chunk
    // c_g = (t&3) ^ ((t>>4)&3) (row>>2 mod 4 is (t>>4)&3 for ALL i since
    // i*64>>2 = i*16 ≡ 0 mod 4). LDS dest stays linear (= uniform + t*16 B).
    const unsigned short* gB = W2t + (size_t)(t >> 2) * D_
                             + (size_t)(((t & 3) ^ ((t >> 4) & 3)) * 8);
    #pragma unroll
    for (int i = 0; i < 8; ++i)
        __builtin_amdgcn_global_load_lds(AS1(gB + (size_t)i * 64 * D_),
            AS3(&Bs[0][(t >> 2) * 32 + (t & 3) * 8 + i * 2048]), 16, 0, 0);

    const int qs = q ^ ((lane16 >> 2) & 3);          // swizzled read chunk

    f32x4 acc[8] = {};
    const unsigned short* gA = act + (size_t)(m0 + lane16) * D_ + q * 8;

    int cur = 0;
    for (int k0 = 0; k0 < D_; k0 += 32) {
        __syncthreads();                       // Bs[cur] staged (vmcnt drained)
        bf16x8 av = *(const bf16x8*)(gA + k0); // A direct from global (L2-hot)
        if (k0 + 32 < D_) {
            #pragma unroll
            for (int i = 0; i < 8; ++i)
                __builtin_amdgcn_global_load_lds(AS1(gB + k0 + 32 + (size_t)i * 64 * D_),
                    AS3(&Bs[cur ^ 1][(t >> 2) * 32 + (t & 3) * 8 + i * 2048]), 16, 0, 0);
        }
        #pragma unroll
        for (int nt = 0; nt < 8; ++nt) {
            bf16x8 bv = *(const bf16x8*)&Bs[cur][(w * 128 + nt * 16 + lane16) * 32 + qs * 8];
            acc[nt] = __builtin_amdgcn_mfma_f32_16x16x32_bf16(av, bv, acc[nt], 0, 0, 0);
        }
        cur ^= 1;
    }
    __syncthreads();   // all ds_reads done -> safe to overwrite Bs[0] via S2

    // acc -> S2 (+bias). C/D layout: row = q*4+r, col = lane16 (per n-tile).
    #pragma unroll
    for (int nt = 0; nt < 8; ++nt) {
        int col = w * 128 + nt * 16 + lane16;
        float bs = b2[col];
        #pragma unroll
        for (int r = 0; r < 4; ++r)
            S2[(q * 4 + r) * D_ + col] = acc[nt][r] + bs;
    }
    __syncthreads();

    // Per-wave LN pipeline: wave w owns rows w*4 .. w*4+4 (disjoint).
    const float si0 = img_sizes[b * 2], si1 = img_sizes[b * 2 + 1];
    #pragma unroll 1
    for (int j = 0; j < 4; ++j) {
        const int rho = w * 4 + j;
        const float* bx = boxes + (size_t)(m0 + rho) * 8;
        float xmn = fminf(fminf(bx[0], bx[2]), fminf(bx[4], bx[6]));
        float xmx = fmaxf(fmaxf(bx[0], bx[2]), fmaxf(bx[4], bx[6]));
        float ymn = fminf(fminf(bx[1], bx[3]), fminf(bx[5], bx[7]));
        float ymx = fmaxf(fmaxf(bx[1], bx[3]), fmaxf(bx[5], bx[7]));
        float q0 = xmn / si0, q1 = ymn / si1, q2 = xmx / si0, q3 = ymx / si1;

        float tp[8], su = 0.f, sq = 0.f;
        #pragma unroll
        for (int i = 0; i < 8; ++i) {
            int d = i * 64 + l;
            float v = q0 * Wb[d] + q1 * Wb[512 + d] + q2 * Wb[1024 + d]
                    + q3 * Wb[1536 + d] + bbv[d];
            tp[i] = v; su += v; sq += v * v;
        }
        #pragma unroll
        for (int off = 32; off > 0; off >>= 1) {
            su += __shfl_xor(su, off); sq += __shfl_xor(sq, off);
        }
        float mu = su * (1.0f / 512.0f);
        float rs = rsqrtf(sq * (1.0f / 512.0f) - mu * mu + 1e-5f);

        float sv[8]; su = 0.f; sq = 0.f;
        #pragma unroll
        for (int i = 0; i < 8; ++i) {
            int d = i * 64 + l;
            float p = (tp[i] - mu) * rs * g1[d] + be1[d];
            float s = S2[rho * D_ + d] + p;
            sv[i] = s; su += s; sq += s * s;
        }
        #pragma unroll
        for (int off = 32; off > 0; off >>= 1) {
            su += __shfl_xor(su, off); sq += __shfl_xor(sq, off);
        }
        float mu2 = su * (1.0f / 512.0f);
        float rs2 = rsqrtf(sq * (1.0f / 512.0f) - mu2 * mu2 + 1e-5f);

        #pragma unroll
        for (int i = 0; i < 8; ++i) {
            int d = i * 64 + l;
            S2[rho * D_ + d] = (sv[i] - mu2) * rs2 * g2[d] + be2[d];
        }
    }
    __syncthreads();

    // Transposed store: out[b][d][nb..nb+16). 4 lanes cover 64 B per d.
    const int nb = m0 & 1023;
    float* ob = out + (size_t)b * (D_ * N_) + nb;
    const int dd = t >> 2, part = t & 3;
    #pragma unroll
    for (int i = 0; i < 8; ++i) {
        int d = i * 64 + dd;
        float4 v;
        v.x = S2[(part * 4 + 0) * D_ + d];
        v.y = S2[(part * 4 + 1) * D_ + d];
        v.z = S2[(part * 4 + 2) * D_ + d];
        v.w = S2[(part * 4 + 3) * D_ + d];
        *(float4*)(ob + (size_t)d * N_ + part * 4) = v;
    }
    if (t < 16) out[(size_t)B_ * D_ * N_ + m0 + t] = 1.0f;   // masks
}

// ---------------------------------------------------------------------------
// FALLBACK path kernels (ws too small): round-1 NCHW gather + weight convert
// + 64x64 VGPR-staged GEMM + standalone tail/mask.
// ---------------------------------------------------------------------------
__global__ __launch_bounds__(256) void k_convert(
    const float* __restrict__ W1, const float* __restrict__ W2,
    unsigned short* __restrict__ W1t, unsigned short* __restrict__ W2t)
{
    int i = blockIdx.x * 256 + threadIdx.x;
    const int n1 = INK_ * D_;
    if (i < n1) {
        int n = i / INK_, k = i % INK_;
        W1t[i] = f2bf(W1[(size_t)k * D_ + n]);
    } else {
        int j = i - n1;
        if (j < D_ * D_) {
            int n = j / D_, k = j % D_;
            W2t[j] = f2bf(W2[(size_t)k * D_ + n]);
        }
    }
}

__global__ __launch_bounds__(256) void k_roi(
    const float* __restrict__ feats, const float* __restrict__ boxes,
    unsigned short* __restrict__ flat)
{
    __shared__ int   so[36][4];
    __shared__ float sw[36][4];
    const int bn = blockIdx.x;
    const int b  = bn >> 10;
    const int t  = threadIdx.x;

    if (t < 36) {
        const float* bx = boxes + (size_t)bn * 8;
        float xmn = fminf(fminf(bx[0], bx[2]), fminf(bx[4], bx[6]));
        float xmx = fmaxf(fmaxf(bx[0], bx[2]), fmaxf(bx[4], bx[6]));
        float ymn = fminf(fminf(bx[1], bx[3]), fminf(bx[5], bx[7]));
        float ymx = fmaxf(fmaxf(bx[1], bx[3]), fmaxf(bx[5], bx[7]));
        float sx1 = xmn * 0.25f, sy1 = ymn * 0.25f;
        float sx2 = xmx * 0.25f, sy2 = ymx * 0.25f;
        float rw = fmaxf(sx2 - sx1, 1.0f), rh = fmaxf(sy2 - sy1, 1.0f);
        float binw = rw * (1.0f / 3.0f), binh = rh * (1.0f / 3.0f);
        int row = t / 6, col = t % 6;
        float y = sy1 + (row * 0.5f + 0.25f) * binh;
        float x = sx1 + (col * 0.5f + 0.25f) * binw;
        float valid = (y > -1.0f && y < 256.0f && x > -1.0f && x < 256.0f) ? 1.0f : 0.0f;
        y = fminf(fmaxf(y, 0.0f), 255.0f);
        x = fminf(fmaxf(x, 0.0f), 255.0f);
        int y0 = (int)floorf(y), x0 = (int)floorf(x);
        int y1 = min(y0 + 1, 255), x1 = min(x0 + 1, 255);
        float ly = y - (float)y0, lx = x - (float)x0;
        float hy = 1.0f - ly, hx = 1.0f - lx;
        float m = 0.25f * valid;
        so[t][0] = y0 * HW_ + x0;  so[t][1] = y0 * HW_ + x1;
        so[t][2] = y1 * HW_ + x0;  so[t][3] = y1 * HW_ + x1;
        sw[t][0] = hy * hx * m;    sw[t][1] = hy * lx * m;
        sw[t][2] = ly * hx * m;    sw[t][3] = ly * lx * m;
    }
    __syncthreads();

    const float* base = feats + ((size_t)(b * CIN_ + t) << 16);
    float acc[9] = {0.f,0.f,0.f,0.f,0.f,0.f,0.f,0.f,0.f};
    #pragma unroll
    for (int j = 0; j < 36; ++j) {
        const int bin = ((j / 6) >> 1) * 3 + ((j % 6) >> 1);
        float v = sw[j][0] * base[so[j][0]] + sw[j][1] * base[so[j][1]]
                + sw[j][2] * base[so[j][2]] + sw[j][3] * base[so[j][3]];
        acc[bin] += v;
    }
    unsigned short* dst = flat + (size_t)bn * INK_ + t * 9;
    #pragma unroll
    for (int k = 0; k < 9; ++k) dst[k] = f2bf(acc[k]);
}

template <int K, bool RELU_BF16OUT>
__global__ __launch_bounds__(256) void k_gemm(
    const unsigned short* __restrict__ A,
    const unsigned short* __restrict__ Bt,
    const float* __restrict__ bias,
    unsigned short* __restrict__ Cbf,
    float* __restrict__ Cf)
{
    __shared__ __align__(16) unsigned short Asl[64 * 40];
    __shared__ __align__(16) unsigned short Bsl[64 * 40];

    const int t  = threadIdx.x;
    const int m0 = blockIdx.x * 64;
    const int n0 = blockIdx.y * 64;
    const int w  = t >> 6;
    const int l  = t & 63;
    const int lane16 = l & 15;
    const int q  = l >> 4;

    f32x4 acc[4] = {};

    const int srow = t >> 2;
    const int sch  = t & 3;
    const unsigned short* ga = A  + (size_t)(m0 + srow) * K + sch * 8;
    const unsigned short* gb = Bt + (size_t)(n0 + srow) * K + sch * 8;
    unsigned short* la = &Asl[srow * 40 + sch * 8];
    unsigned short* lb = &Bsl[srow * 40 + sch * 8];

    for (int k0 = 0; k0 < K; k0 += 32) {
        __syncthreads();
        *(bf16x8*)la = *(const bf16x8*)(ga + k0);
        *(bf16x8*)lb = *(const bf16x8*)(gb + k0);
        __syncthreads();
        bf16x8 af = *(const bf16x8*)&Asl[(w * 16 + lane16) * 40 + q * 8];
        #pragma unroll
        for (int nt = 0; nt < 4; ++nt) {
            bf16x8 bfv = *(const bf16x8*)&Bsl[(nt * 16 + lane16) * 40 + q * 8];
            acc[nt] = __builtin_amdgcn_mfma_f32_16x16x32_bf16(af, bfv, acc[nt], 0, 0, 0);
        }
    }

    #pragma unroll
    for (int nt = 0; nt < 4; ++nt) {
        int col = n0 + nt * 16 + lane16;
        float bs = bias[col];
        #pragma unroll
        for (int r = 0; r < 4; ++r) {
            int rowg = m0 + w * 16 + q * 4 + r;
            float v = acc[nt][r] + bs;
            if constexpr (RELU_BF16OUT) {
                v = fmaxf(v, 0.0f);
                Cbf[(size_t)rowg * D_ + col] = f2bf(v);
            } else {
                Cf[(size_t)rowg * D_ + col] = v;
            }
        }
    }
}

__device__ __forceinline__ void breduce2(float& a, float& b, float* red, int t) {
    #pragma unroll
    for (int off = 32; off > 0; off >>= 1) {
        a += __shfl_down(a, off);
        b += __shfl_down(b, off);
    }
    int w = t >> 6;
    if ((t & 63) == 0) { red[w] = a; red[4 + w] = b; }
    __syncthreads();
    a = red[0] + red[1] + red[2] + red[3];
    b = red[4] + red[5] + red[6] + red[7];
    __syncthreads();
}

__global__ __launch_bounds__(256) void k_tail(
    const float* __restrict__ lines, const float* __restrict__ boxes,
    const float* __restrict__ img_sizes,
    const float* __restrict__ Wb,  const float* __restrict__ bbv,
    const float* __restrict__ g1,  const float* __restrict__ be1,
    const float* __restrict__ g2,  const float* __restrict__ be2,
    float* __restrict__ out)
{
    __shared__ float red[8];
    const int row = blockIdx.x;
    const int b = row >> 10, n = row & 1023;
    const int t = threadIdx.x;

    const float* bx = boxes + (size_t)row * 8;
    float xmn = fminf(fminf(bx[0], bx[2]), fminf(bx[4], bx[6]));
    float xmx = fmaxf(fmaxf(bx[0], bx[2]), fmaxf(bx[4], bx[6]));
    float ymn = fminf(fminf(bx[1], bx[3]), fminf(bx[5], bx[7]));
    float ymx = fmaxf(fmaxf(bx[1], bx[3]), fmaxf(bx[5], bx[7]));
    float s0 = img_sizes[b * 2], s1 = img_sizes[b * 2 + 1];
    float q0 = xmn / s0, q1 = ymn / s1, q2 = xmx / s0, q3 = ymx / s1;

    float tv[2], sv[2];
    float sum = 0.f, sumsq = 0.f;
    #pragma unroll
    for (int i = 0; i < 2; ++i) {
        int d = t + i * 256;
        float v = q0 * Wb[d] + q1 * Wb[512 + d] + q2 * Wb[1024 + d] + q3 * Wb[1536 + d] + bbv[d];
        tv[i] = v; sum += v; sumsq += v * v;
    }
    breduce2(sum, sumsq, red, t);
    float mu = sum * (1.0f / 512.0f);
    float var = sumsq * (1.0f / 512.0f) - mu * mu;
    float rs = rsqrtf(var + 1e-5f);

    sum = 0.f; sumsq = 0.f;
    #pragma unroll
    for (int i = 0; i < 2; ++i) {
        int d = t + i * 256;
        float p = (tv[i] - mu) * rs * g1[d] + be1[d];
        float s = lines[(size_t)row * D_ + d] + p;
        sv[i] = s; sum += s; sumsq += s * s;
    }
    breduce2(sum, sumsq, red, t);
    float mu2 = sum * (1.0f / 512.0f);
    float var2 = sumsq * (1.0f / 512.0f) - mu2 * mu2;
    float rs2 = rsqrtf(var2 + 1e-5f);

    #pragma unroll
    for (int i = 0; i < 2; ++i) {
        int d = t + i * 256;
        float o = (sv[i] - mu2) * rs2 * g2[d] + be2[d];
        out[(size_t)b * (D_ * N_) + (size_t)d * N_ + n] = o;
    }
}

__global__ __launch_bounds__(256) void k_mask(float* __restrict__ out) {
    int i = blockIdx.x * 256 + threadIdx.x;
    if (i < B_ * 32 * 32) out[(size_t)B_ * D_ * N_ + i] = 1.0f;
}

// ---------------------------------------------------------------------------
extern "C" void kernel_launch(void* const* d_in, const int* in_sizes, int n_in,
                              void* d_out, int out_size, void* d_ws, size_t ws_size,
                              hipStream_t stream)
{
    const float* feats = (const float*)d_in[0];
    const float* boxes = (const float*)d_in[1];
    const float* img   = (const float*)d_in[2];
    const float* W1    = (const float*)d_in[3];
    const float* b1    = (const float*)d_in[4];
    const float* W2    = (const float*)d_in[5];
    const float* b2    = (const float*)d_in[6];
    const float* Wb    = (const float*)d_in[7];
    const float* bbv   = (const float*)d_in[8];
    const float* g1    = (const float*)d_in[9];
    const float* be1   = (const float*)d_in[10];
    const float* g2    = (const float*)d_in[11];
    const float* be2   = (const float*)d_in[12];
    float* out = (float*)d_out;
    char* ws = (char*)d_ws;

    // Fast-path ws layout (bytes):
    const size_t OFF_FEATST = 0;                         // bf16 4x65536x256 = 134,217,728
    const size_t OFF_W1T    = 134217728;                 // bf16 512x2304   =   2,359,296
    const size_t OFF_W2T    = 136577024;                 // bf16 512x512    =     524,288
    const size_t OFF_FLAT   = 137101312;                 // bf16 4096x2304  =  18,874,368
    const size_t OFF_ACT    = 155975680;                 // bf16 4096x512   =   4,194,304
    const size_t NEED       = 160169984;

    if (ws_size >= NEED) {
        unsigned short* featsT = (unsigned short*)(ws + OFF_FEATST);
        unsigned short* W1t    = (unsigned short*)(ws + OFF_W1T);
        unsigned short* W2t    = (unsigned short*)(ws + OFF_W2T);
        unsigned short* flat   = (unsigned short*)(ws + OFF_FLAT);
        unsigned short* act    = (unsigned short*)(ws + OFF_ACT);

        // feats (B,CIN,HW) f32 -> featsT (B,HW,CIN) bf16
        k_t64<unsigned short><<<dim3(HW_*HW_/64, CIN_/64, B_), 256, 0, stream>>>(
            feats, featsT, CIN_, HW_*HW_, (size_t)CIN_*HW_*HW_, (size_t)CIN_*HW_*HW_);
        // W1 (2304,512) -> W1t (512,2304) bf16 ; W2 (512,512) -> W2t
        k_t64<unsigned short><<<dim3(D_/64, INK_/64, 1), 256, 0, stream>>>(
            W1, W1t, INK_, D_, 0, 0);
        k_t64<unsigned short><<<dim3(D_/64, D_/64, 1), 256, 0, stream>>>(
            W2, W2t, D_, D_, 0, 0);

        k_roi3<<<BN_/4, 256, 0, stream>>>(featsT, boxes, flat);

        dim3 gg(32, 8);   // M/128 x N/64 = 256 blocks
        k_gemmB<INK_, true><<<gg, 256, 0, stream>>>(flat, W1t, b1, act, nullptr);

        // Fused GEMM2 + LN pipeline + transposed store + mask
        k_fuse2<<<BN_/16, 256, 0, stream>>>(act, W2t, b2, boxes, img,
                                            Wb, bbv, g1, be1, g2, be2, out);
    } else {
        // Fallback: round-1 path (34,340,864 bytes of ws)
        unsigned short* W1t  = (unsigned short*)(ws);
        unsigned short* W2t  = (unsigned short*)(ws + 2359296);
        unsigned short* flat = (unsigned short*)(ws + 2883584);
        unsigned short* act  = (unsigned short*)(ws + 21757952);
        float*          lines= (float*)(ws + 25952256);

        const int convTotal = INK_ * D_ + D_ * D_;
        k_convert<<<(convTotal + 255) / 256, 256, 0, stream>>>(W1, W2, W1t, W2t);
        k_roi<<<BN_, 256, 0, stream>>>(feats, boxes, flat);
        dim3 gg(64, 8);
        k_gemm<INK_, true ><<<gg, 256, 0, stream>>>(flat, W1t, b1, act, nullptr);
        k_gemm<D_,   false><<<gg, 256, 0, stream>>>(act,  W2t, b2, nullptr, lines);
        k_tail<<<BN_, 256, 0, stream>>>(lines, boxes, img, Wb, bbv, g1, be1, g2, be2, out);
        k_mask<<<16, 256, 0, stream>>>(out);
    }
}